// Round 7
// baseline (14247.784 us; speedup 1.0000x reference)
//
#include <hip/hip_runtime.h>

#define NCONE 8
#define NDIM 24          // NC*3
#define PGD_ITERS 100
#define BATCH 65536
#define BLOCKT 256       // 1 elem/thread; 1024 waves = 1 wave/SIMD chip-wide
#define POW_ITERS 80
#define NPK 150          // 300 unique symmetric P entries, fp16-packed in pairs

typedef _Float16 half2v __attribute__((ext_vector_type(2)));

__device__ __forceinline__ float fast_rsq(float x) { return __builtin_amdgcn_rsqf(x); }

// ---- band-major enumeration of the upper triangle -------------------------
// List order: d = j-i ascending; within a band, i ascending.
// Band d has NDIM-d entries. This clusters each packed register's uses
// adjacently in the emitted FMA stream (the R6 lesson: scattered uses cost
// one AGPR->VGPR shuttle copy EACH; clustered uses share one).
constexpr int b2i(int u) {
    int d = 0;
    while (u >= NDIM - d) { u -= NDIM - d; ++d; }
    return u;
}
constexpr int b2j(int u) {
    int d = 0;
    while (u >= NDIM - d) { u -= NDIM - d; ++d; }
    return u + d;
}

// SOC projection, rsqrt-only form (saves v_rcp + cndmask vs reference form).
// scale = coef/n = coef*rsq ; n = n2*rsq = sqrt(n2). Continuous at the
// cone boundaries, so ulp-level n errors can't flip a branch discontinuously.
__device__ __forceinline__ void soc_proj(float& t, float& x0, float& x1) {
    float n2  = fmaf(x0, x0, x1 * x1);
    float n2s = fmaxf(n2, 1e-30f);          // guard n2=0 (l0=0 never hits it, belt+braces)
    float rsq = fast_rsq(n2s);
    float n   = n2s * rsq;
    float coef = 0.5f * (t + n);
    float sc   = coef * rsq;
    bool inside = (n <= t);
    bool below  = (n <= -t);
    float tn = inside ? t    : (below ? 0.0f : coef);
    float s  = inside ? 1.0f : (below ? 0.0f : sc);
    t = tn; x0 *= s; x1 *= s;
}

// g(f32) += li(f32) * f16-half of pk — one full-rate VALU op (verified R6:
// assembles on gfx950, numerics match fp16-P absmax 0.031).
#define FMA_MIX_LO(g_, li_, pk_)                                               \
    asm("v_fma_mix_f32 %0, %1, %2, %0 op_sel:[0,0,0] op_sel_hi:[0,1,0]"        \
        : "+v"(g_) : "v"(li_), "v"(pk_))
#define FMA_MIX_HI(g_, li_, pk_)                                               \
    asm("v_fma_mix_f32 %0, %1, %2, %0 op_sel:[0,1,0] op_sel_hi:[0,1,0]"        \
        : "+v"(g_) : "v"(li_), "v"(pk_))

// ---------------------------------------------------------------------------
// Fused kernel, v7.
//
// R1: LICM hoist of LDS-P -> 256 VGPR + 2.7 GB scratch, 836 us.
// R2: LDS broadcast @1 wave/SIMD: ds_read latency exposed, 349 us.
// R3: 2 elem/thread -> half the SIMDs idle, 396 us.
// R4: SMEM-streamed P: s_load stalls @1 wave/SIMD, 878 us.
// R5: f16 P in regs: allocator parked it in AGPRs + extract/cvt path, 338 us.
// R6: inline v_fma_mix fixed the math path but NOT the shuttle: RA inserts
//     one v_accvgpr_read per USE (576/iter) because each reg's uses are
//     scattered -> 1630 insts/iter, VALUBusy 45%, 304 us.
//
// v7: band-major packing clusters each reg's 2-4 uses adjacently -> RA's
// live-range split pays ~1 copy/reg/iter (150, batchable) instead of 576
// serialized ones. Mirrored accumulation into h[] keeps consecutive FMA
// targets distinct (no RMW chains). Projection: one rsqrt per cone.
// ~930 insts/iter -> ~79 us loop @ 1 wave/SIMD.
// ---------------------------------------------------------------------------
__global__ __launch_bounds__(BLOCKT, 1) void pgd_fused(const float* __restrict__ P,
                                                       const float* __restrict__ q,
                                                       float* __restrict__ out) {
    __shared__ __align__(16) float sP[NDIM * NDIM];   // staging: pow-iter + pack
    __shared__ float sQ[BLOCKT * (NDIM + 1)];         // coalescing buffer, stride 25

    const int tid  = threadIdx.x;
    const int base = blockIdx.x * (BLOCKT * NDIM);

    for (int i = tid; i < NDIM * NDIM; i += BLOCKT)
        sP[i] = P[i];
    for (int idx = tid; idx < BLOCKT * NDIM; idx += BLOCKT) {
        int r = idx / NDIM;
        int c = idx - r * NDIM;
        sQ[r * (NDIM + 1) + c] = q[base + idx];
    }
    __syncthreads();

    // --- step = 1/lambda_max(P): per-wave power iteration + Rayleigh ---
    // (zero inter-block state — R2's graph-replay divergence lesson)
    const int lane = tid & 63;
    float step;
    {
        float p[NDIM];
#pragma unroll
        for (int j = 0; j < NDIM; ++j)
            p[j] = (lane < NDIM) ? sP[lane * NDIM + j] : 0.0f;
        float v = (lane < NDIM) ? (1.0f + 0.01f * (float)lane) : 0.0f;

        for (int it = 0; it < POW_ITERS; ++it) {
            float w = 0.0f;
#pragma unroll
            for (int j = 0; j < NDIM; ++j)
                w = fmaf(p[j], __shfl(v, j, 64), w);
            float n2 = w * w;
#pragma unroll
            for (int off = 32; off >= 1; off >>= 1)
                n2 += __shfl_xor(n2, off, 64);
            v = w * rsqrtf(n2);
        }
        float w = 0.0f;
#pragma unroll
        for (int j = 0; j < NDIM; ++j)
            w = fmaf(p[j], __shfl(v, j, 64), w);
        float num = v * w;
        float den = v * v;
#pragma unroll
        for (int off = 32; off >= 1; off >>= 1) {
            num += __shfl_xor(num, off, 64);
            den += __shfl_xor(den, off, 64);
        }
        step = den / num;   // identical on every lane/wave/block
    }

    // --- pack upper triangle of symmetric P, BAND-MAJOR, into 150 regs ---
    unsigned phw[NPK];
#pragma unroll
    for (int k = 0; k < NPK; ++k) {
        float a = sP[b2i(2 * k)     * NDIM + b2j(2 * k)];
        float b = sP[b2i(2 * k + 1) * NDIM + b2j(2 * k + 1)];
        half2v hv;
        hv[0] = (_Float16)a;
        hv[1] = (_Float16)b;
        phw[k] = __builtin_bit_cast(unsigned, hv);
    }

    // --- per-thread state ---
    float lq[NDIM], l[NDIM];
#pragma unroll
    for (int j = 0; j < NDIM; ++j) {
        lq[j] = sQ[tid * (NDIM + 1) + j];
        l[j]  = 0.0f;
    }

#pragma clang loop unroll(disable)
    for (int it = 0; it < PGD_ITERS; ++it) {
        float g[NDIM], h[NDIM];
#pragma unroll
        for (int j = 0; j < NDIM; ++j) {
            g[j] = lq[j];
            h[j] = 0.0f;
        }

        // g/h += P l — band-major symmetric walk, 576 v_fma_mix total.
        // Each phw[k]'s uses are adjacent -> ~1 shuttle copy per reg if RA
        // parks phw in AGPRs; consecutive targets distinct -> no RMW chains.
#pragma unroll
        for (int k = 0; k < NPK; ++k) {
            unsigned pk = phw[k];
#pragma unroll
            for (int hf = 0; hf < 2; ++hf) {
                const int u = 2 * k + hf;    // compile-time under full unroll
                const int i = b2i(u);
                const int j = b2j(u);
                if (i == j) {
                    if (hf == 0) { FMA_MIX_LO(g[i], l[i], pk); }
                    else         { FMA_MIX_HI(g[i], l[i], pk); }
                } else {
                    if (hf == 0) { FMA_MIX_LO(g[j], l[i], pk);
                                   FMA_MIX_LO(h[i], l[j], pk); }
                    else         { FMA_MIX_HI(g[j], l[i], pk);
                                   FMA_MIX_HI(h[i], l[j], pk); }
                }
            }
        }

        // y = l - step*(g + h)   (g already contains lq)
#pragma unroll
        for (int j = 0; j < NDIM; ++j) {
            float s1 = g[j] + h[j];
            g[j] = fmaf(-step, s1, l[j]);
        }

        // project onto product of 8 SOCs
#pragma unroll
        for (int c = 0; c < NCONE; ++c)
            soc_proj(g[c], g[NCONE + 2 * c], g[NCONE + 2 * c + 1]);

#pragma unroll
        for (int j = 0; j < NDIM; ++j)
            l[j] = g[j];
    }

    // --- coalesced store through padded LDS ---
    __syncthreads();
#pragma unroll
    for (int j = 0; j < NDIM; ++j)
        sQ[tid * (NDIM + 1) + j] = l[j];
    __syncthreads();
    for (int idx = tid; idx < BLOCKT * NDIM; idx += BLOCKT) {
        int r = idx / NDIM;
        int c = idx - r * NDIM;
        out[base + idx] = sQ[r * (NDIM + 1) + c];
    }
}

extern "C" void kernel_launch(void* const* d_in, const int* in_sizes, int n_in,
                              void* d_out, int out_size, void* d_ws, size_t ws_size,
                              hipStream_t stream) {
    const float* P = (const float*)d_in[0];   // (1, 24, 24) fp32
    const float* q = (const float*)d_in[1];   // (65536, 24, 1) fp32
    float* out     = (float*)d_out;           // (65536, 24) fp32
    (void)d_ws; (void)ws_size;

    pgd_fused<<<BATCH / BLOCKT, BLOCKT, 0, stream>>>(P, q, out);
}